// Round 17
// baseline (283.969 us; speedup 1.0000x reference)
//
#include <hip/hip_runtime.h>
#include <stdint.h>

#define BI 128
#define BT 128
#define KIMG 36
#define LCAP 64
#define DD 1024
#define MP 48        // imgs K padded to 3x16 for MFMA alignment

typedef _Float16 h4 __attribute__((ext_vector_type(4)));
typedef _Float16 h8 __attribute__((ext_vector_type(8)));
typedef float f4 __attribute__((ext_vector_type(4)));

__device__ __forceinline__ float wave_red_sum(float v) {
#pragma unroll
  for (int o = 1; o < 64; o <<= 1) v += __shfl_xor(v, o, 64);
  return v;
}
__device__ __forceinline__ float wave_red_max(float v) {
#pragma unroll
  for (int o = 1; o < 64; o <<= 1) v = fmaxf(v, __shfl_xor(v, o, 64));
  return v;
}

// ---------------------------------------------------------------------------
// Kernel 1: add EPS, L2-normalize rows over D=1024, cast to fp16.
// ONE WAVE PER ROW (4 rows / 256-thread block): pure shuffle reduction.
// BOTH outputs are FRAGMENT-MAJOR, STEP-CONTIGUOUS (512-half tiles; within a
// tile, half-offset = lane*8 + (kk&7) with lane = (kk>>3)*16 + rr — exactly
// the mfma_16x16x32 A/B fragment layout, so a GEMM wave's fragment load is
// one contiguous coalesced 1 KB segment):
//   A[pair p 0..63][t 0..31][rowtile rt 0..5][512]   (rt: img0 rt0-2, img1 rt3-5)
//   B[bx 0..31][t 0..31][coltile ct 0..15][512]
// ---------------------------------------------------------------------------
__global__ __launch_bounds__(256) void norm_kernel(
    const float* __restrict__ imgs, const float* __restrict__ caps,
    _Float16* __restrict__ Afm, _Float16* __restrict__ Bfm) {
  int lane = threadIdx.x & 63;
  int wv = threadIdx.x >> 6;
  int row = blockIdx.x * 4 + wv;          // 0 .. BI*MP + BT*LCAP - 1

  const float* src = nullptr;
  _Float16* base;
  int rr;                                 // row-in-tile 0..15
  size_t tile0;                           // tile index at t=0
  int tstride;                            // tiles per k-step
  bool zero = false;

  if (row < BI * MP) {
    int i = row / MP, kr = row - i * MP;
    int p = i >> 1;
    int row96 = (i & 1) * MP + kr;
    int rt = row96 >> 4;
    rr = row96 & 15;
    tile0 = (size_t)(p * 32) * 6 + rt;
    tstride = 6;
    base = Afm;
    if (kr >= KIMG) zero = true;          // padding rows: write zeros
    else src = imgs + ((size_t)i * KIMG + kr) * DD;
  } else {
    int r = row - BI * MP;                // 0..8191 = cap*64 + word
    int cap = r >> 6, word = r & 63;
    int bx = cap >> 2;
    int ct = (cap & 3) * 4 + (word >> 4);
    rr = word & 15;
    tile0 = (size_t)(bx * 32) * 16 + ct;
    tstride = 16;
    base = Bfm;
    src = caps + (size_t)r * DD;
  }

  float4 x[4];
  float ss = 0.f;
  if (!zero) {
#pragma unroll
    for (int seg = 0; seg < 4; ++seg) {
      x[seg] = ((const float4*)src)[lane + 64 * seg];
      x[seg].x += 1e-6f; x[seg].y += 1e-6f; x[seg].z += 1e-6f; x[seg].w += 1e-6f;
      ss += x[seg].x * x[seg].x + x[seg].y * x[seg].y +
            x[seg].z * x[seg].z + x[seg].w * x[seg].w;
    }
    ss = wave_red_sum(ss);
  }
  float scale = zero ? 0.f : rsqrtf(ss);
#pragma unroll
  for (int seg = 0; seg < 4; ++seg) {
    h4 o = {};
    if (!zero) {
      o[0] = (_Float16)(x[seg].x * scale);
      o[1] = (_Float16)(x[seg].y * scale);
      o[2] = (_Float16)(x[seg].z * scale);
      o[3] = (_Float16)(x[seg].w * scale);
    }
    int k = 4 * (lane + 64 * seg);
    int t = k >> 5, kk = k & 31;
    int sub = ((kk >> 3) * 16 + rr) * 8 + (kk & 7);
    *(h4*)(base + (tile0 + (size_t)t * tstride) * 512 + sub) = o;
  }
}

// ---------------------------------------------------------------------------
// Kernel 2: NO LDS, NO BARRIERS. 2 images x 4 captions per block (96x256),
// wave w = caption w, but the 4 waves are fully INDEPENDENT (A is read
// directly from L2/L3 in fragment-major form — Common-mistake #7: don't
// LDS-stage what the cache serves). Per step: 6 A-frag + 4 B-frag coalesced
// 1 KB loads, ping-pong prefetched one step ahead, 24 MFMA. Latency hiding
// = TLP (12 waves/CU free-running) + 1-deep prefetch; no sync of any kind.
// Register-resident masked-softmax epilogue unchanged.
// ---------------------------------------------------------------------------
__global__ __launch_bounds__(256, 3) void sims_kernel(
    const _Float16* __restrict__ Afm, const _Float16* __restrict__ Bfm,
    const int* __restrict__ img_lens, const int* __restrict__ cap_lens,
    float* __restrict__ out) {
  int tid = threadIdx.x;
  int lane = tid & 63;
  int w = tid >> 6;       // wave = caption within quad

  // ---- XCD-aware remap (R7): 4 caption-quads per XCD, by shared x4 ----
  int wgid = blockIdx.x;
  int xcd = wgid & 7;
  int slot = wgid >> 3;            // 0..255
  int bx = 4 * xcd + (slot & 3);   // caption quad 0..31
  int by = slot >> 2;              // image pair 0..63

  int fr = lane & 15;
  int fq = lane >> 4;

  // ---- fragment-major bases (one pointer each; per-step stride) ----
  const _Float16* ap = Afm + ((size_t)(by * 32) * 6) * 512 + lane * 8;
  const _Float16* bp = Bfm + ((size_t)(bx * 32) * 16 + w * 4) * 512 + lane * 8;

  f4 acc[6][4] = {};
  h8 afA[6], afB[6], bfA[4], bfB[4];

  auto LOADA = [&](h8(&af)[6], int t) {
#pragma unroll
    for (int mi = 0; mi < 6; ++mi)
      af[mi] = *(const h8*)(ap + (size_t)(t * 6 + mi) * 512);
  };
  auto LOADB = [&](h8(&bf)[4], int t) {
#pragma unroll
    for (int ni = 0; ni < 4; ++ni)
      bf[ni] = *(const h8*)(bp + (size_t)(t * 16 + ni) * 512);
  };
  auto MFMA = [&](h8(&af)[6], h8(&bf)[4]) {
    __builtin_amdgcn_s_setprio(1);
#pragma unroll
    for (int mi = 0; mi < 6; ++mi)
#pragma unroll
      for (int ni = 0; ni < 4; ++ni)
        acc[mi][ni] = __builtin_amdgcn_mfma_f32_16x16x32_f16(
            af[mi], bf[ni], acc[mi][ni], 0, 0, 0);
    __builtin_amdgcn_s_setprio(0);
  };

  // ---- prologue + ping-pong main loop (no sync anywhere) ----
  LOADA(afA, 0);
  LOADB(bfA, 0);
  for (int tt = 0; tt < 30; tt += 2) {
    LOADA(afB, tt + 1);
    LOADB(bfB, tt + 1);
    MFMA(afA, bfA);
    LOADA(afA, tt + 2);
    LOADB(bfA, tt + 2);
    MFMA(afB, bfB);
  }
  LOADA(afB, 31);
  LOADB(bfB, 31);
  MFMA(afA, bfA);
  MFMA(afB, bfB);

  // ---- register epilogue: C/D layout col=16*ni+fr, row=16*mi+4*fq+j ----
  int t = bx * 4 + w;
  int Lt = cap_lens[t];

#pragma unroll
  for (int img = 0; img < 2; ++img) {
    int Ki = img_lens[2 * by + img];

    float m = -1e30f;
#pragma unroll
    for (int mi = 0; mi < 3; ++mi)
#pragma unroll
      for (int ni = 0; ni < 4; ++ni)
#pragma unroll
        for (int j = 0; j < 4; ++j) {
          bool valid = (16 * mi + 4 * fq + j < Ki) && (16 * ni + fr < Lt);
          if (valid) m = fmaxf(m, acc[3 * img + mi][ni][j]);
        }
    m = wave_red_max(m);

    float rowe[3][4] = {}, rowes[3][4] = {}, cole[4] = {}, coles[4] = {};
#pragma unroll
    for (int mi = 0; mi < 3; ++mi)
#pragma unroll
      for (int ni = 0; ni < 4; ++ni)
#pragma unroll
        for (int j = 0; j < 4; ++j) {
          float s = acc[3 * img + mi][ni][j];
          bool valid = (16 * mi + 4 * fq + j < Ki) && (16 * ni + fr < Lt);
          float e = valid ? __expf((s - m) * 20.0f) : 0.f;  // 1/LAMB = 20
          float es = e * s;
          rowe[mi][j] += e;
          rowes[mi][j] += es;
          cole[ni] += e;
          coles[ni] += es;
        }

    // v2t: per row, reduce over cols (fr lanes), then accumulate rows
    float part = 0.f;
#pragma unroll
    for (int mi = 0; mi < 3; ++mi)
#pragma unroll
      for (int j = 0; j < 4; ++j) {
        float Re = rowe[mi][j], Res = rowes[mi][j];
#pragma unroll
        for (int o = 1; o < 16; o <<= 1) {
          Re += __shfl_xor(Re, o, 64);
          Res += __shfl_xor(Res, o, 64);
        }
        int row = 16 * mi + 4 * fq + j;
        if (fr == 0 && row < Ki) part += (Res / Re) * (0.5f / (float)Ki);
      }
    // t2v: per col, reduce over rows (fq lanes), then accumulate cols
#pragma unroll
    for (int ni = 0; ni < 4; ++ni) {
      float Ce = cole[ni], Ces = coles[ni];
#pragma unroll
      for (int o = 16; o < 64; o <<= 1) {
        Ce += __shfl_xor(Ce, o, 64);
        Ces += __shfl_xor(Ces, o, 64);
      }
      int l = 16 * ni + fr;
      if (fq == 0 && l < Lt) part += (Ces / Ce) * (0.5f / (float)Lt);
    }
    float sim = wave_red_sum(part);
    if (lane == 0) out[(size_t)(2 * by + img) * BT + t] = sim;
  }
}

extern "C" void kernel_launch(void* const* d_in, const int* in_sizes, int n_in,
                              void* d_out, int out_size, void* d_ws, size_t ws_size,
                              hipStream_t stream) {
  // setup_inputs order: img_cls, imgs, cap_cls, caps, img_lens, cap_lens
  const float* imgs = (const float*)d_in[1];
  const float* caps = (const float*)d_in[3];
  const int* img_lens = (const int*)d_in[4];
  const int* cap_lens = (const int*)d_in[5];
  float* out = (float*)d_out;

  _Float16* Afm = (_Float16*)d_ws;                   // fragment-major A, 12.6 MB
  _Float16* Bfm = Afm + (size_t)BI * MP * DD;        // fragment-major B, 16.8 MB

  norm_kernel<<<(BI * MP + BT * LCAP) / 4, 256, 0, stream>>>(imgs, caps, Afm, Bfm);
  sims_kernel<<<2048, 256, 0, stream>>>(Afm, Bfm, img_lens, cap_lens, out);
}

// Round 18
// 132.230 us; speedup vs baseline: 2.1475x; 2.1475x over previous
//
#include <hip/hip_runtime.h>
#include <stdint.h>

#define BI 128
#define BT 128
#define KIMG 36
#define LCAP 64
#define DD 1024
#define MP 48        // imgs K padded to 3x16 for MFMA alignment
#define MB 96        // rows per block = 2 padded images
#define NB 256       // cols per block = 4 captions
#define ABUF 6144    // one A staging buffer: 96 rows x 64 B

typedef _Float16 h4 __attribute__((ext_vector_type(4)));
typedef _Float16 h8 __attribute__((ext_vector_type(8)));
typedef float f4 __attribute__((ext_vector_type(4)));

__device__ __forceinline__ float wave_red_sum(float v) {
#pragma unroll
  for (int o = 1; o < 64; o <<= 1) v += __shfl_xor(v, o, 64);
  return v;
}
__device__ __forceinline__ float wave_red_max(float v) {
#pragma unroll
  for (int o = 1; o < 64; o <<= 1) v = fmaxf(v, __shfl_xor(v, o, 64));
  return v;
}

// ---------------------------------------------------------------------------
// Kernel 1: add EPS, L2-normalize rows over D=1024, cast to fp16.
// ONE WAVE PER ROW (4 rows / 256-thread block): pure shuffle reduction, no
// LDS, no __syncthreads. Each lane owns 4 float4 at stride-64.
// imgs -> padded row-major [BI*MP][DD] (rows 36..47 of each image = 0).
// caps -> FRAGMENT-MAJOR Bh: tile (r/16, k/32) of 512 halves; within a tile
// half-offset = lane*8 where lane = (kk>>3)*16 + (r&15), kk = k&31. This makes
// a GEMM wave's bf[ni] fragment load one contiguous, coalesced 1 KB segment.
// ---------------------------------------------------------------------------
__global__ __launch_bounds__(256) void norm_kernel(
    const float* __restrict__ imgs, const float* __restrict__ caps,
    _Float16* __restrict__ Ah, _Float16* __restrict__ Bh) {
  int lane = threadIdx.x & 63;
  int wv = threadIdx.x >> 6;
  int row = blockIdx.x * 4 + wv;          // 0 .. BI*MP + BT*LCAP - 1
  const float* src;
  bool isCap;
  int r = 0;
  if (row < BI * MP) {
    int i = row / MP, k = row - i * MP;
    isCap = false;
    if (k >= KIMG) {                      // zero padding rows (wave-uniform)
      h4 z = {};
#pragma unroll
      for (int seg = 0; seg < 4; ++seg)
        ((h4*)(Ah + (size_t)row * DD))[lane + 64 * seg] = z;
      return;
    }
    src = imgs + ((size_t)i * KIMG + k) * DD;
  } else {
    r = row - BI * MP;
    isCap = true;
    src = caps + (size_t)r * DD;
  }
  float4 x[4];
  float ss = 0.f;
#pragma unroll
  for (int seg = 0; seg < 4; ++seg) {
    x[seg] = ((const float4*)src)[lane + 64 * seg];
    x[seg].x += 1e-6f; x[seg].y += 1e-6f; x[seg].z += 1e-6f; x[seg].w += 1e-6f;
    ss += x[seg].x * x[seg].x + x[seg].y * x[seg].y +
          x[seg].z * x[seg].z + x[seg].w * x[seg].w;
  }
  ss = wave_red_sum(ss);
  float scale = rsqrtf(ss);
#pragma unroll
  for (int seg = 0; seg < 4; ++seg) {
    h4 o;
    o[0] = (_Float16)(x[seg].x * scale);
    o[1] = (_Float16)(x[seg].y * scale);
    o[2] = (_Float16)(x[seg].z * scale);
    o[3] = (_Float16)(x[seg].w * scale);
    if (!isCap) {
      ((h4*)(Ah + (size_t)row * DD))[lane + 64 * seg] = o;
    } else {
      int k = 4 * (lane + 64 * seg);
      size_t tile = (size_t)(r >> 4) * 32 + (k >> 5);
      int sub = ((k >> 3) & 3) * 128 + (r & 15) * 8 + (k & 7);
      *(h4*)(Bh + tile * 512 + sub) = o;
    }
  }
}

// ---------------------------------------------------------------------------
// Kernel 2 (byte-exact R11 champion): 2 images x 4 captions per block
// (96x256), wave w = caption w. B never touches LDS:
//  - A (shared by 4 waves): swizzled LDS dbuf, 6 KB/step (12.3 KB total).
//  - B (wave-private): fragment-major coalesced 1KB global->VGPR loads,
//    ping-pong prefetched one step ahead, drained by end-of-step barrier.
// A swizzle: 16B-slot involution s ^= (s>>3)&7; LDS dest linear, global
// source pre-swizzled (rule 21), frag reads apply same involution.
// ---------------------------------------------------------------------------
__global__ __launch_bounds__(256, 3) void sims_kernel(
    const _Float16* __restrict__ Ah, const _Float16* __restrict__ Bh,
    const int* __restrict__ img_lens, const int* __restrict__ cap_lens,
    float* __restrict__ out) {
  __shared__ char stage[2 * ABUF] __attribute__((aligned(16)));

  int tid = threadIdx.x;
  int lane = tid & 63;
  int w = tid >> 6;       // wave = caption within quad

  // ---- XCD-aware remap (R7): 4 caption-quads per XCD, by shared x4 ----
  int wgid = blockIdx.x;
  int xcd = wgid & 7;
  int slot = wgid >> 3;            // 0..255
  int bx = 4 * xcd + (slot & 3);   // caption quad 0..31
  int by = slot >> 2;              // image pair 0..63

  int fr = lane & 15;
  int fq = lane >> 4;

  const size_t arow0 = (size_t)by * MB;

  // ---- A staging: 6 chunks of 1 KB; waves own {0-1},{2-3},{4},{5} ----
  const int c0 = (w < 2) ? 2 * w : w + 2;
  const int nch = (w < 2) ? 2 : 1;
  int s0 = c0 * 64 + lane;
  int sw0 = s0 ^ ((s0 >> 3) & 7);
  const _Float16* gpA = Ah + (arow0 + (sw0 >> 2)) * DD + (sw0 & 3) * 8;
  const int lds0 = c0 * 1024 + lane * 16;

  // ---- af LDS read base: swizzle XOR is mi-invariant (64mi ≡ 0 mod 8) ----
  int sl = 4 * fr + fq;
  const int aoff0 = (sl ^ ((sl >> 3) & 7)) * 16;

  // ---- B fragment-major pointers: frag(ni, t) at bp[ni] + 512*t halves ----
  const _Float16* bp[4];
#pragma unroll
  for (int ni = 0; ni < 4; ++ni)
    bp[ni] = Bh + ((size_t)((bx * 16) + 4 * w + ni) * 32) * 512 + lane * 8;

  f4 acc[6][4] = {};
  h8 bfA[4], bfB[4];

  auto STAGE = [&](int buf, int k0) {
    __builtin_amdgcn_global_load_lds(
        (const __attribute__((address_space(1))) void*)(gpA + k0),
        (__attribute__((address_space(3))) void*)(stage + buf * ABUF + lds0), 16, 0, 0);
    if (nch == 2)
      __builtin_amdgcn_global_load_lds(
          (const __attribute__((address_space(1))) void*)(gpA + 16 * DD + k0),
          (__attribute__((address_space(3))) void*)(stage + buf * ABUF + lds0 + 1024), 16, 0, 0);
  };
  auto LOADB = [&](h8(&bf)[4], int t) {
#pragma unroll
    for (int ni = 0; ni < 4; ++ni) bf[ni] = *(const h8*)(bp[ni] + 512 * t);
  };
  // one step: prefetch A(t+1)+B(t+1), compute(t), barrier (drains prefetch)
  auto BODY = [&](int t, int parity, h8(&cur)[4], h8(&nxt)[4]) {
    if (t < 31) {
      STAGE(parity ^ 1, 32 * (t + 1));   // buf(t+1): reads of it at t-1 done
      LOADB(nxt, t + 1);
    }
    const char* rb = stage + parity * ABUF;
    h8 af[6];
#pragma unroll
    for (int mi = 0; mi < 6; ++mi)
      af[mi] = *(const h8*)(rb + aoff0 + 1024 * mi);
    __builtin_amdgcn_s_setprio(1);
#pragma unroll
    for (int mi = 0; mi < 6; ++mi)
#pragma unroll
      for (int ni = 0; ni < 4; ++ni)
        acc[mi][ni] = __builtin_amdgcn_mfma_f32_16x16x32_f16(
            af[mi], cur[ni], acc[mi][ni], 0, 0, 0);
    __builtin_amdgcn_s_setprio(0);
    __syncthreads();   // vmcnt(0)+barrier: A(t+1)/B(t+1) had full compute to land
  };

  // ---- prologue: A(0)->buf0, B(0)->regs ----
  STAGE(0, 0);
  LOADB(bfA, 0);
  __syncthreads();

  for (int tt = 0; tt < 32; tt += 2) {
    BODY(tt, 0, bfA, bfB);
    BODY(tt + 1, 1, bfB, bfA);
  }

  // ---- register epilogue: C/D layout col=16*ni+fr, row=16*mi+4*fq+j ----
  int t = bx * 4 + w;
  int Lt = cap_lens[t];

#pragma unroll
  for (int img = 0; img < 2; ++img) {
    int Ki = img_lens[2 * by + img];

    float m = -1e30f;
#pragma unroll
    for (int mi = 0; mi < 3; ++mi)
#pragma unroll
      for (int ni = 0; ni < 4; ++ni)
#pragma unroll
        for (int j = 0; j < 4; ++j) {
          bool valid = (16 * mi + 4 * fq + j < Ki) && (16 * ni + fr < Lt);
          if (valid) m = fmaxf(m, acc[3 * img + mi][ni][j]);
        }
    m = wave_red_max(m);

    float rowe[3][4] = {}, rowes[3][4] = {}, cole[4] = {}, coles[4] = {};
#pragma unroll
    for (int mi = 0; mi < 3; ++mi)
#pragma unroll
      for (int ni = 0; ni < 4; ++ni)
#pragma unroll
        for (int j = 0; j < 4; ++j) {
          float s = acc[3 * img + mi][ni][j];
          bool valid = (16 * mi + 4 * fq + j < Ki) && (16 * ni + fr < Lt);
          float e = valid ? __expf((s - m) * 20.0f) : 0.f;  // 1/LAMB = 20
          float es = e * s;
          rowe[mi][j] += e;
          rowes[mi][j] += es;
          cole[ni] += e;
          coles[ni] += es;
        }

    // v2t: per row, reduce over cols (fr lanes), then accumulate rows
    float part = 0.f;
#pragma unroll
    for (int mi = 0; mi < 3; ++mi)
#pragma unroll
      for (int j = 0; j < 4; ++j) {
        float Re = rowe[mi][j], Res = rowes[mi][j];
#pragma unroll
        for (int o = 1; o < 16; o <<= 1) {
          Re += __shfl_xor(Re, o, 64);
          Res += __shfl_xor(Res, o, 64);
        }
        int row = 16 * mi + 4 * fq + j;
        if (fr == 0 && row < Ki) part += (Res / Re) * (0.5f / (float)Ki);
      }
    // t2v: per col, reduce over rows (fq lanes), then accumulate cols
#pragma unroll
    for (int ni = 0; ni < 4; ++ni) {
      float Ce = cole[ni], Ces = coles[ni];
#pragma unroll
      for (int o = 16; o < 64; o <<= 1) {
        Ce += __shfl_xor(Ce, o, 64);
        Ces += __shfl_xor(Ces, o, 64);
      }
      int l = 16 * ni + fr;
      if (fq == 0 && l < Lt) part += (Ces / Ce) * (0.5f / (float)Lt);
    }
    float sim = wave_red_sum(part);
    if (lane == 0) out[(size_t)(2 * by + img) * BT + t] = sim;
  }
}

extern "C" void kernel_launch(void* const* d_in, const int* in_sizes, int n_in,
                              void* d_out, int out_size, void* d_ws, size_t ws_size,
                              hipStream_t stream) {
  // setup_inputs order: img_cls, imgs, cap_cls, caps, img_lens, cap_lens
  const float* imgs = (const float*)d_in[1];
  const float* caps = (const float*)d_in[3];
  const int* img_lens = (const int*)d_in[4];
  const int* cap_lens = (const int*)d_in[5];
  float* out = (float*)d_out;

  _Float16* Ah = (_Float16*)d_ws;                    // [BI*MP][DD] = 12.6 MB
  _Float16* Bh = Ah + (size_t)BI * MP * DD;          // fragment-major, 16.8 MB

  norm_kernel<<<(BI * MP + BT * LCAP) / 4, 256, 0, stream>>>(imgs, caps, Ah, Bh);
  sims_kernel<<<2048, 256, 0, stream>>>(Ah, Bh, img_lens, cap_lens, out);
}